// Round 5
// baseline (591.376 us; speedup 1.0000x reference)
//
#include <hip/hip_runtime.h>
#include <hip/hip_bf16.h>
#include <cstddef>
#include <cstdint>

#define BS 32768
#define MSLOT 2048
#define D 256
#define NCHUNK 128   // i-tiles of 256 rows in k_score

typedef _Float16 f16;
typedef _Float16 f16x8 __attribute__((ext_vector_type(8)));
typedef float f32x4 __attribute__((ext_vector_type(4)));

#define WAITV(n) asm volatile("s_waitcnt vmcnt(" #n ")" ::: "memory")
#define WAITLGKM asm volatile("s_waitcnt lgkmcnt(0)" ::: "memory")

__device__ __forceinline__ void barrier_raw() {
    asm volatile("" ::: "memory");
    __builtin_amdgcn_s_barrier();
    asm volatile("" ::: "memory");
}

__device__ __forceinline__ void lds_cp16(void* dst, const void* src) {
    __builtin_amdgcn_global_load_lds(
        (const __attribute__((address_space(1))) void*)src,
        (__attribute__((address_space(3))) void*)dst, 16, 0, 0);
}

__device__ __forceinline__ void top2_merge(float& a0, int& ai0, float& a1, int& ai1,
                                           float b0, int bi0, float b1, int bi1)
{
    bool bt = (b0 > a0) || (b0 == a0 && bi0 < ai0);
    float n0, n1; int ni0, ni1;
    if (bt) {
        n0 = b0; ni0 = bi0;
        bool s2 = (b1 > a0) || (b1 == a0 && bi1 < ai0);
        n1 = s2 ? b1 : a0; ni1 = s2 ? bi1 : ai0;
    } else {
        n0 = a0; ni0 = ai0;
        bool s2 = (b0 > a1) || (b0 == a1 && bi0 < ai1);
        n1 = s2 ? b0 : a1; ni1 = s2 ? bi0 : ai1;
    }
    a0 = n0; ai0 = ni0; a1 = n1; ai1 = ni1;
}

// ---------------------------------------------------------------- prep: normalize + f16x2 split (q scaled by 256)
__global__ __launch_bounds__(256) void k_prepq(const float* __restrict__ query,
                                               float* __restrict__ out0,
                                               f16* __restrict__ qcat)
{
    __shared__ float sbuf[4];
    const int i = blockIdx.x, t = threadIdx.x;
    float v = query[(size_t)i * D + t];
    float ss = v * v;
#pragma unroll
    for (int off = 32; off; off >>= 1) ss += __shfl_xor(ss, off, 64);
    if ((t & 63) == 0) sbuf[t >> 6] = ss;
    __syncthreads();
    float tot = (sbuf[0] + sbuf[1]) + (sbuf[2] + sbuf[3]);
    float n = fmaxf(sqrtf(tot), 1e-12f);
    float qv = v / n;
    out0[(size_t)i * (2 * D) + t] = qv;
    float qs = qv * 256.0f;
    f16 h = (f16)qs;
    f16 lo = (f16)(qs - (float)h);
    qcat[(size_t)i * 512 + t] = h;
    qcat[(size_t)i * 512 + 256 + t] = lo;
}

// ---------------------------------------------------------------- prep: memory split + f16 transpose + zero qupd
__global__ __launch_bounds__(256) void k_prepm(const float* __restrict__ memory,
                                               f16* __restrict__ mcat,
                                               f16* __restrict__ memT,
                                               float* __restrict__ qupd)
{
    const int j = blockIdx.x, t = threadIdx.x;
    float m = memory[(size_t)j * D + t];
    f16 h = (f16)m;
    f16 lo = (f16)(m - (float)h);
    mcat[(size_t)j * 512 + t] = h;
    mcat[(size_t)j * 512 + 256 + t] = lo;
    memT[(size_t)t * MSLOT + j] = h;   // [n=dim][k=slot]
    qupd[(size_t)j * D + t] = 0.0f;
}

// ---------------------------------------------------------------- score GEMM (unchanged from R4)
__global__ __launch_bounds__(512, 2) void k_score(const f16* __restrict__ qcat,
                                                  const f16* __restrict__ mcat,
                                                  float* __restrict__ out2,
                                                  float* __restrict__ colpart)
{
    __shared__ __align__(16) f16 As[2][256 * 64];
    __shared__ __align__(16) f16 Bs[2][256 * 64];
    __shared__ float sepM[8][4][16], sepS[8][4][16];

    const int tid = threadIdx.x;
    const int l = tid & 63, w = tid >> 6;
    const int wr = w >> 2, wc = w & 3;
    const int lk = (l >> 4) & 3, lm = l & 15;
    const int sr = tid >> 3, sch = tid & 7;

    const int hflat = blockIdx.y * 8 + blockIdx.x;
    const int xcd = hflat & 7, kk8 = hflat >> 3;
    const int by = xcd * 16 + (kk8 >> 3);
    const int bx = kk8 & 7;
    const int i0 = by * 256, j0 = bx * 256;

#define STAGE(buf, t) do {                                                          \
    int k0_ = (t) * 64;                                                             \
    int ao_ = ((t) < 8 ? 0 : 256) + (k0_ & 255);                                    \
    int bo_ = ((((t) >= 4) && ((t) < 8)) ? 256 : 0) + (k0_ & 255);                  \
    _Pragma("unroll")                                                               \
    for (int c = 0; c < 4; ++c) {                                                   \
        int r_ = c * 64 + sr;                                                       \
        int g_ = sch ^ ((r_ >> 1) & 7);                                             \
        lds_cp16(&As[buf][(c * 512 + tid) * 8],                                     \
                 qcat + (size_t)(i0 + r_) * 512 + ao_ + g_ * 8);                    \
        lds_cp16(&Bs[buf][(c * 512 + tid) * 8],                                     \
                 mcat + (size_t)(j0 + r_) * 512 + bo_ + g_ * 8);                    \
    }                                                                               \
} while (0)

    f32x4 acc[8][4] = {};

    STAGE(0, 0);
    STAGE(1, 1);

    for (int t = 0; t < 12; ++t) {
        const int cur = t & 1;
        if (t < 11) { WAITV(8); } else { WAITV(0); }
        barrier_raw();
        const f16* Ab = As[cur];
        const f16* Bb = Bs[cur];
        __builtin_amdgcn_s_setprio(1);
#pragma unroll
        for (int kk = 0; kk < 2; ++kk) {
            f16x8 bf[4];
#pragma unroll
            for (int ni = 0; ni < 4; ++ni) {
                int r = wc * 64 + ni * 16 + lm;
                int slot = (kk * 4 + lk) ^ (lm >> 1);
                bf[ni] = *(const f16x8*)(Bb + r * 64 + slot * 8);
            }
#pragma unroll
            for (int mi = 0; mi < 8; ++mi) {
                int r = wr * 128 + mi * 16 + lm;
                int slot = (kk * 4 + lk) ^ (lm >> 1);
                f16x8 af = *(const f16x8*)(Ab + r * 64 + slot * 8);
#pragma unroll
                for (int ni = 0; ni < 4; ++ni)
                    acc[mi][ni] = __builtin_amdgcn_mfma_f32_16x16x32_f16(af, bf[ni], acc[mi][ni], 0, 0, 0);
            }
        }
        __builtin_amdgcn_s_setprio(0);
        barrier_raw();
        if (t < 10) STAGE(cur, t + 2);
    }
#undef STAGE

    const float sc = 1.0f / 256.0f;
#pragma unroll
    for (int mi = 0; mi < 8; ++mi)
#pragma unroll
        for (int ni = 0; ni < 4; ++ni)
            acc[mi][ni] *= sc;

#pragma unroll
    for (int mi = 0; mi < 8; ++mi) {
        int row = i0 + wr * 128 + mi * 16 + lk * 4;
#pragma unroll
        for (int ni = 0; ni < 4; ++ni) {
            int col = j0 + wc * 64 + ni * 16 + lm;
#pragma unroll
            for (int r = 0; r < 4; ++r)
                out2[(size_t)(row + r) * MSLOT + col] = acc[mi][ni][r];
        }
    }

    float cm[4], cs[4];
#pragma unroll
    for (int ni = 0; ni < 4; ++ni) {
        float mx = -INFINITY;
#pragma unroll
        for (int mi = 0; mi < 8; ++mi)
#pragma unroll
            for (int r = 0; r < 4; ++r) mx = fmaxf(mx, acc[mi][ni][r]);
        float sm = 0.0f;
#pragma unroll
        for (int mi = 0; mi < 8; ++mi)
#pragma unroll
            for (int r = 0; r < 4; ++r) sm += __expf(acc[mi][ni][r] - mx);
#pragma unroll
        for (int off = 16; off <= 32; off <<= 1) {
            float om = __shfl_xor(mx, off, 64);
            float os = __shfl_xor(sm, off, 64);
            float nm = fmaxf(mx, om);
            sm = sm * __expf(mx - nm) + os * __expf(om - nm);
            mx = nm;
        }
        cm[ni] = mx; cs[ni] = sm;
    }
    if (l < 16) {
#pragma unroll
        for (int ni = 0; ni < 4; ++ni) { sepM[w][ni][l] = cm[ni]; sepS[w][ni][l] = cs[ni]; }
    }
    __syncthreads();
    if (w < 4 && l < 16) {
#pragma unroll
        for (int ni = 0; ni < 4; ++ni) {
            float m1 = sepM[w][ni][l], s1 = sepS[w][ni][l];
            float m2 = sepM[w + 4][ni][l], s2 = sepS[w + 4][ni][l];
            float nm = fmaxf(m1, m2);
            float ns = s1 * __expf(m1 - nm) + s2 * __expf(m2 - nm);
            int col = j0 + w * 64 + ni * 16 + l;
            size_t o = ((size_t)by * MSLOT + col) * 2;
            colpart[o + 0] = nm;
            colpart[o + 1] = ns;
        }
    }
}

// ---------------------------------------------------------------- column merge
__global__ __launch_bounds__(256) void k_colmerge(const float* __restrict__ colpart,
                                                  float* __restrict__ colM,
                                                  float* __restrict__ colSinv,
                                                  float* __restrict__ colC)
{
    const int col = blockIdx.x * 256 + threadIdx.x;
    float m = -INFINITY, s = 0.0f;
    for (int c = 0; c < NCHUNK; ++c) {
        size_t o = ((size_t)c * MSLOT + col) * 2;
        float pm = colpart[o + 0], ps = colpart[o + 1];
        float nm = fmaxf(m, pm);
        s = s * __expf(m - nm) + ps * __expf(pm - nm);
        m = nm;
    }
    colM[col] = m;
    colSinv[col] = 1.0f / s;
    colC[col] = m + __logf(s);
}

// ---------------------------------------------------------------- fused: row stats + losses + softmax transforms + concat GEMM
// Block = 64 rows x 2048 cols. 512 threads (8 waves). LDS: A 16KB + B 64KB = 80KB -> 2 blocks/CU.
__global__ __launch_bounds__(512, 2) void k_transcat(float* out2,                       // raw score in, sfxq out
                                                     float* __restrict__ out3,          // sfxm out
                                                     float* __restrict__ out0,          // q left | concat right
                                                     const f16* __restrict__ memT,      // [256][2048]
                                                     const float* __restrict__ colM,
                                                     const float* __restrict__ colSinv,
                                                     const float* __restrict__ colC,
                                                     const float* __restrict__ memory,
                                                     int* __restrict__ jstarA, float* __restrict__ wA,
                                                     float* __restrict__ gpart, float* __restrict__ spart)
{
    __shared__ __align__(16) f16 Atile[64 * 128];    // 16 KB
    __shared__ __align__(16) f16 Btile[256 * 128];   // 64 KB

    const int tid = threadIdx.x;
    const int l = tid & 63, w = tid >> 6;
    const int wr = w >> 2, wc = w & 3;
    const int lk = (l >> 4) & 3, lm = l & 15;
    const int rl = tid >> 3, q8 = tid & 7;           // pass-1/2 row-local, col-eighth
    const int grow = blockIdx.x * 64 + rl;
    float* srow = out2 + (size_t)grow * MSLOT;

    // ================= pass 1: row stats (max, sumexp, top2, argmax) =================
    float pm = -INFINITY, ps = 0.0f;
    float t0v = -INFINITY, t1v = -INFINITY; int t0i = 0x7fffffff, t1i = 0x7fffffff;
    float av = -INFINITY, araw = 0.0f; int ai = 0x7fffffff;

    for (int kc = 0; kc < 16; ++kc) {
        const int c0 = kc * 128 + q8 * 16;
        float xv[16], cc[16];
#pragma unroll
        for (int u = 0; u < 4; ++u) {
            float4 a = *(const float4*)(srow + c0 + u * 4);
            xv[u * 4 + 0] = a.x; xv[u * 4 + 1] = a.y; xv[u * 4 + 2] = a.z; xv[u * 4 + 3] = a.w;
            float4 b = *(const float4*)(colC + c0 + u * 4);
            cc[u * 4 + 0] = b.x; cc[u * 4 + 1] = b.y; cc[u * 4 + 2] = b.z; cc[u * 4 + 3] = b.w;
        }
        // chunk max then merge into running (pm, ps)
        float lmax = xv[0];
#pragma unroll
        for (int u = 1; u < 16; ++u) lmax = fmaxf(lmax, xv[u]);
        float nm = fmaxf(pm, lmax);
        ps *= __expf(pm - nm);
        pm = nm;
#pragma unroll
        for (int u = 0; u < 16; ++u) ps += __expf(xv[u] - pm);
        // top2 of raw + argmax(score - colC)
#pragma unroll
        for (int u = 0; u < 16; ++u) {
            int idx = c0 + u; float cv = xv[u];
            if (cv > t0v)      { t1v = t0v; t1i = t0i; t0v = cv; t0i = idx; }
            else if (cv > t1v) { t1v = cv; t1i = idx; }
            float x = cv - cc[u];
            if (x > av) { av = x; ai = idx; araw = cv; }
        }
    }
    // merge across the 8 lanes of this row (lanes differ in bits 0..2)
#pragma unroll
    for (int off = 1; off < 8; off <<= 1) {
        float opm = __shfl_xor(pm, off, 64), ops = __shfl_xor(ps, off, 64);
        float nm = fmaxf(pm, opm);
        ps = ps * __expf(pm - nm) + ops * __expf(opm - nm);
        pm = nm;
        float b0 = __shfl_xor(t0v, off, 64), b1 = __shfl_xor(t1v, off, 64);
        int  bi0 = __shfl_xor(t0i, off, 64), bi1 = __shfl_xor(t1i, off, 64);
        top2_merge(t0v, t0i, t1v, t1i, b0, bi0, b1, bi1);
        float ov = __shfl_xor(av, off, 64), oraw = __shfl_xor(araw, off, 64);
        int   oi = __shfl_xor(ai, off, 64);
        if (ov > av || (ov == av && oi < ai)) { av = ov; ai = oi; araw = oraw; }
    }
    const float rm = pm;
    const float rsinv = 1.0f / ps;

    // losses for this row (8 lanes cooperate)
    {
        float g = 0.0f, dp = 0.0f, dn = 0.0f;
        const float* qrow = out0 + (size_t)grow * (2 * D) + q8 * 32;
        const float* prow = memory + (size_t)t0i * D + q8 * 32;
        const float* nrow = memory + (size_t)t1i * D + q8 * 32;
#pragma unroll
        for (int u = 0; u < 8; ++u) {
            float4 qv = *(const float4*)(qrow + u * 4);
            float4 pv = *(const float4*)(prow + u * 4);
            float4 nv = *(const float4*)(nrow + u * 4);
#pragma unroll
            for (int e = 0; e < 4; ++e) {
                float qe = ((const float*)&qv)[e];
                float pe = ((const float*)&pv)[e];
                float ne = ((const float*)&nv)[e];
                float dq = qe - pe;
                g += dq * dq;
                float a = dq + 1e-6f;        dp += a * a;
                float b = (qe - ne) + 1e-6f; dn += b * b;
            }
        }
#pragma unroll
        for (int off = 1; off < 8; off <<= 1) {
            g  += __shfl_xor(g, off, 64);
            dp += __shfl_xor(dp, off, 64);
            dn += __shfl_xor(dn, off, 64);
        }
        if (q8 == 0) {
            gpart[grow] = g;
            spart[grow] = fmaxf(sqrtf(dp) - sqrtf(dn) + 1.0f, 0.0f);
            jstarA[grow] = ai;
            wA[grow] = __expf(araw - colM[ai]);
        }
    }

    // ================= pass 2: transform + concat GEMM =================
    f32x4 acc[2][4] = {};
    const int i0row = blockIdx.x * 64;

    for (int kc = 0; kc < 16; ++kc) {
        barrier_raw();   // previous chunk's MFMA done with Atile/Btile
        const int c0 = kc * 128 + q8 * 16;

        // score re-read (issued first: oldest in vm queue)
        float4 s0 = *(const float4*)(srow + c0 + 0);
        float4 s1 = *(const float4*)(srow + c0 + 4);
        float4 s2 = *(const float4*)(srow + c0 + 8);
        float4 s3 = *(const float4*)(srow + c0 + 12);

        // B-stage: memT chunk [256 n][128 k] with inverse-swizzled source
#pragma unroll
        for (int c = 0; c < 8; ++c) {
            int f = c * 512 + tid;
            int n = f >> 4, s = f & 15;
            int g = s ^ (n & 15);
            lds_cp16(&Btile[f * 8], memT + (size_t)n * MSLOT + kc * 128 + g * 8);
        }

        float v[16];
        v[0] = s0.x; v[1] = s0.y; v[2] = s0.z; v[3] = s0.w;
        v[4] = s1.x; v[5] = s1.y; v[6] = s1.z; v[7] = s1.w;
        v[8] = s2.x; v[9] = s2.y; v[10] = s2.z; v[11] = s2.w;
        v[12] = s3.x; v[13] = s3.y; v[14] = s3.z; v[15] = s3.w;

        float cM[16], cS[16];
#pragma unroll
        for (int u = 0; u < 4; ++u) {
            float4 a = *(const float4*)(colM + c0 + u * 4);
            cM[u * 4 + 0] = a.x; cM[u * 4 + 1] = a.y; cM[u * 4 + 2] = a.z; cM[u * 4 + 3] = a.w;
            float4 b = *(const float4*)(colSinv + c0 + u * 4);
            cS[u * 4 + 0] = b.x; cS[u * 4 + 1] = b.y; cS[u * 4 + 2] = b.z; cS[u * 4 + 3] = b.w;
        }

        float oq[16], om[16];
#pragma unroll
        for (int u = 0; u < 16; ++u) {
            oq[u] = __expf(v[u] - cM[u]) * cS[u];
            om[u] = __expf(v[u] - rm) * rsinv;
        }
        // stores (youngest in vm queue)
        float4 w0 = {oq[0], oq[1], oq[2], oq[3]},  w1 = {oq[4], oq[5], oq[6], oq[7]};
        float4 w2 = {oq[8], oq[9], oq[10], oq[11]}, w3 = {oq[12], oq[13], oq[14], oq[15]};
        *(float4*)(srow + c0 + 0) = w0;  *(float4*)(srow + c0 + 4) = w1;
        *(float4*)(srow + c0 + 8) = w2;  *(float4*)(srow + c0 + 12) = w3;
        float4 m0 = {om[0], om[1], om[2], om[3]},  m1 = {om[4], om[5], om[6], om[7]};
        float4 m2 = {om[8], om[9], om[10], om[11]}, m3 = {om[12], om[13], om[14], om[15]};
        float* mrow = out3 + (size_t)grow * MSLOT + c0;
        *(float4*)(mrow + 0) = m0;  *(float4*)(mrow + 4) = m1;
        *(float4*)(mrow + 8) = m2;  *(float4*)(mrow + 12) = m3;

        // A-tile ds_write (f16, XOR-swizzled slots)
        f16x8 h0, h1;
#pragma unroll
        for (int u = 0; u < 8; ++u) { h0[u] = (f16)om[u]; h1[u] = (f16)om[u + 8]; }
        int sw0 = (q8 * 2 + 0) ^ (rl & 15);
        int sw1 = (q8 * 2 + 1) ^ (rl & 15);
        *(f16x8*)(Atile + rl * 128 + sw0 * 8) = h0;
        *(f16x8*)(Atile + rl * 128 + sw1 * 8) = h1;

        WAITLGKM;           // A-tile ds_writes complete
        WAITV(8);           // B-stage (oldest 8) landed; oq/om stores may still fly
        barrier_raw();
        __builtin_amdgcn_sched_barrier(0);

        // MFMA: out tile 64x256, per wave 32 rows x 64 cols, K=128
        __builtin_amdgcn_s_setprio(1);
#pragma unroll
        for (int kk = 0; kk < 4; ++kk) {
            f16x8 bf[4];
#pragma unroll
            for (int ni = 0; ni < 4; ++ni) {
                int n = wc * 64 + ni * 16 + lm;
                int slot = (kk * 4 + lk) ^ (n & 15);
                bf[ni] = *(const f16x8*)(Btile + n * 128 + slot * 8);
            }
#pragma unroll
            for (int mi = 0; mi < 2; ++mi) {
                int r = wr * 32 + mi * 16 + lm;
                int slot = (kk * 4 + lk) ^ (r & 15);
                f16x8 af = *(const f16x8*)(Atile + r * 128 + slot * 8);
#pragma unroll
                for (int ni = 0; ni < 4; ++ni)
                    acc[mi][ni] = __builtin_amdgcn_mfma_f32_16x16x32_f16(af, bf[ni], acc[mi][ni], 0, 0, 0);
            }
        }
        __builtin_amdgcn_s_setprio(0);
    }

    // epilogue: concat result -> out0 right half
#pragma unroll
    for (int mi = 0; mi < 2; ++mi) {
        int row = i0row + wr * 32 + mi * 16 + lk * 4;
#pragma unroll
        for (int ni = 0; ni < 4; ++ni) {
            int col = wc * 64 + ni * 16 + lm;
#pragma unroll
            for (int r = 0; r < 4; ++r)
                out0[(size_t)(row + r) * (2 * D) + D + col] = acc[mi][ni][r];
        }
    }
}

// ---------------------------------------------------------------- segment sum (atomic scatter, f16 source)
__global__ __launch_bounds__(256) void k_scatter(const f16* __restrict__ qcat,
                                                 const int* __restrict__ jstarA,
                                                 const float* __restrict__ wA,
                                                 float* __restrict__ qupd)
{
    const int i = blockIdx.x, t = threadIdx.x;
    const int j = jstarA[i];
    const float wv = wA[i] * (1.0f / 256.0f);
    float qv = (float)qcat[(size_t)i * 512 + t] + (float)qcat[(size_t)i * 512 + 256 + t];
    unsafeAtomicAdd(&qupd[(size_t)j * D + t], wv * qv);
}

// ---------------------------------------------------------------- updated memory
__global__ __launch_bounds__(256) void k_updmem(const float* __restrict__ qupd,
                                                const float* __restrict__ memory,
                                                float* __restrict__ out1)
{
    __shared__ float sbuf[4];
    const int j = blockIdx.x, t = threadIdx.x;
    float v = qupd[(size_t)j * D + t] + memory[(size_t)j * D + t];
    float ss = v * v;
#pragma unroll
    for (int off = 32; off; off >>= 1) ss += __shfl_xor(ss, off, 64);
    if ((t & 63) == 0) sbuf[t >> 6] = ss;
    __syncthreads();
    float tot = (sbuf[0] + sbuf[1]) + (sbuf[2] + sbuf[3]);
    float n = fmaxf(sqrtf(tot), 1e-12f);
    out1[(size_t)j * D + t] = v / n;
}

// ---------------------------------------------------------------- loss reduce
__global__ __launch_bounds__(256) void k_losses(const float* __restrict__ gpart,
                                                const float* __restrict__ spart,
                                                float* __restrict__ out45)
{
    __shared__ float sf[256];
    const int t = threadIdx.x;
    float g = 0.f, s = 0.f;
    for (int i = t; i < BS; i += 256) { g += gpart[i]; s += spart[i]; }
    sf[t] = g; __syncthreads();
    for (int off = 128; off; off >>= 1) { if (t < off) sf[t] += sf[t + off]; __syncthreads(); }
    float gt = sf[0]; __syncthreads();
    sf[t] = s; __syncthreads();
    for (int off = 128; off; off >>= 1) { if (t < off) sf[t] += sf[t + off]; __syncthreads(); }
    float st = sf[0];
    if (t == 0) {
        out45[0] = gt / (float)((size_t)BS * D);
        out45[1] = st / (float)BS;
    }
}

// ---------------------------------------------------------------- launcher
extern "C" void kernel_launch(void* const* d_in, const int* in_sizes, int n_in,
                              void* d_out, int out_size, void* d_ws, size_t ws_size,
                              hipStream_t stream)
{
    const float* query  = (const float*)d_in[0];
    const float* memory = (const float*)d_in[1];

    float* out  = (float*)d_out;
    float* out0 = out;                                   // update_query  [BS][2D]
    float* out1 = out0 + (size_t)BS * 2 * D;             // updated_memory[M][D]
    float* out2 = out1 + (size_t)MSLOT * D;              // sfx_score_query [BS][M]
    float* out3 = out2 + (size_t)BS * MSLOT;             // sfx_score_memory[BS][M]
    float* out45 = out3 + (size_t)BS * MSLOT;            // two scalars

    f16* qcat = (f16*)d_ws;                              // BS*512  [qh|ql]
    f16* mcat = qcat + (size_t)BS * 512;                 // M*512   [mh|ml]
    f16* memT = mcat + (size_t)MSLOT * 512;              // D*M
    float* colpart = (float*)(memT + (size_t)D * MSLOT); // NCHUNK*M*2
    float* colM    = colpart + (size_t)NCHUNK * MSLOT * 2;
    float* colSinv = colM + MSLOT;
    float* colC    = colSinv + MSLOT;
    float* wA      = colC + MSLOT;                       // BS
    int*   jstarA  = (int*)(wA + BS);                    // BS
    float* gpart   = (float*)(jstarA + BS);              // BS
    float* spart   = gpart + BS;                         // BS
    float* qupd    = spart + BS;                         // M*D

    // 1) prep (prepm also zeroes qupd)
    k_prepq<<<BS, 256, 0, stream>>>(query, out0, qcat);
    k_prepm<<<MSLOT, 256, 0, stream>>>(memory, mcat, memT, qupd);

    // 2) score GEMM (K=768 f16 MFMA, 256^2 tile, counted-vmcnt pipeline) + col partials
    k_score<<<dim3(MSLOT / 256, BS / 256), 512, 0, stream>>>(qcat, mcat, out2, colpart);

    // 3) column merge
    k_colmerge<<<MSLOT / 256, 256, 0, stream>>>(colpart, colM, colSinv, colC);

    // 4) fused row stats + losses + transforms + concat GEMM
    k_transcat<<<BS / 64, 512, 0, stream>>>(out2, out3, out0, memT,
                                            colM, colSinv, colC, memory,
                                            jstarA, wA, gpart, spart);

    // 5) segment-sum memory update
    k_scatter<<<BS, 256, 0, stream>>>(qcat, jstarA, wA, qupd);
    k_updmem<<<MSLOT, 256, 0, stream>>>(qupd, memory, out1);

    // 6) losses
    k_losses<<<1, 256, 0, stream>>>(gpart, spart, out45);
}